// Round 2
// baseline (58.254 us; speedup 1.0000x reference)
//
#include <hip/hip_runtime.h>

#define BATCH 1024
#define NUM_GENES 20000
#define NONGENE_DIM 64
#define EMB_DIM 32
#define INPUT_DIM (NUM_GENES + NONGENE_DIM)   // 20064
#define ROWS_PER_BLOCK 32
#define TILE_GENES 1024                       // 256 threads * 4 genes
#define N_TILES (NUM_GENES / TILE_GENES)      // 20 (exact: 20*1024=20480? NO)
// careful: 20000 / 1024 = 19.53 -> NOT exact. Use tile = 1000 genes? See below.

// 20000 = 25 * 800 = 20 * 1000. Use TILE of 1000 genes (250 float4 per row,
// 250 threads active of 256) so tiling is exact: 20 tiles * 1000 genes.
#undef TILE_GENES
#define TILE_GENES 1000
#define TILE_F4 (TILE_GENES / 4)              // 250 float4 columns per tile

__global__ __launch_bounds__(256)
void dlge_fused(const float* __restrict__ x,
                const float* __restrict__ emb,
                const float* __restrict__ W,
                const float* __restrict__ bptr,
                float* __restrict__ y) {
    __shared__ float s_ng[ROWS_PER_BLOCK];

    const int t    = threadIdx.x;
    const int tile = blockIdx.x;              // 0..19
    const int rowg = blockIdx.y;              // 0..31
    const int row0 = rowg * ROWS_PER_BLOCK;

    // ---- phase 0: ng_term for this block's 32 rows (8 lanes per row) ----
    {
        const int r = t >> 3;                 // 0..31
        const int k = t & 7;                  // 0..7
        const int row = row0 + r;
        const float4* n4 = reinterpret_cast<const float4*>(
            x + (size_t)row * INPUT_DIM + NUM_GENES);
        const float4 a = n4[k];               // dims 4k .. 4k+3
        const float4 c = n4[k + 8];           // dims 32+4k .. 32+4k+3
        float p = a.x * W[4 * k + 0] + a.y * W[4 * k + 1]
                + a.z * W[4 * k + 2] + a.w * W[4 * k + 3]
                + c.x * W[32 + 4 * k + 0] + c.y * W[32 + 4 * k + 1]
                + c.z * W[32 + 4 * k + 2] + c.w * W[32 + 4 * k + 3];
        p += __shfl_down(p, 4, 8);
        p += __shfl_down(p, 2, 8);
        p += __shfl_down(p, 1, 8);
        if (k == 0) s_ng[r] = p + bptr[0];
    }

    // ---- phase 1: gene_term for this thread's 4 genes, kept in registers ----
    // thread t covers genes g0..g0+3 (only threads with t < 250 are active)
    const bool active = (t < TILE_F4);
    const int g0 = tile * TILE_GENES + t * 4;
    float gt0 = 0.f, gt1 = 0.f, gt2 = 0.f, gt3 = 0.f;
    if (active) {
        float acc[4];
#pragma unroll
        for (int q = 0; q < 4; ++q) {
            const float4* e4 = reinterpret_cast<const float4*>(
                emb + (size_t)(g0 + q) * EMB_DIM);
            float a = 0.f;
#pragma unroll
            for (int k = 0; k < EMB_DIM / 4; ++k) {
                const float4 e = e4[k];
                a += e.x * W[NONGENE_DIM + 1 + 4 * k + 0]
                   + e.y * W[NONGENE_DIM + 1 + 4 * k + 1]
                   + e.z * W[NONGENE_DIM + 1 + 4 * k + 2]
                   + e.w * W[NONGENE_DIM + 1 + 4 * k + 3];
            }
            acc[q] = a;
        }
        gt0 = acc[0]; gt1 = acc[1]; gt2 = acc[2]; gt3 = acc[3];
    }

    __syncthreads();

    // ---- phase 2: stream 32 rows of this tile ----
    if (!active) return;
    const float wx = W[NONGENE_DIM];
    const int j = tile * TILE_F4 + t;         // float4 index within row (0..4999)

#pragma unroll 8
    for (int r = 0; r < ROWS_PER_BLOCK; ++r) {
        const int row = row0 + r;
        const float s = s_ng[r];
        const float4 x4 = reinterpret_cast<const float4*>(
            x + (size_t)row * INPUT_DIM)[j];
        float4 o;
        o.x = s + x4.x * wx + gt0;
        o.y = s + x4.y * wx + gt1;
        o.z = s + x4.z * wx + gt2;
        o.w = s + x4.w * wx + gt3;
        reinterpret_cast<float4*>(y + (size_t)row * NUM_GENES)[j] = o;
    }
}

extern "C" void kernel_launch(void* const* d_in, const int* in_sizes, int n_in,
                              void* d_out, int out_size, void* d_ws, size_t ws_size,
                              hipStream_t stream) {
    const float* x   = (const float*)d_in[0];
    const float* emb = (const float*)d_in[1];
    const float* W   = (const float*)d_in[2];
    const float* b   = (const float*)d_in[3];
    float* y = (float*)d_out;

    dim3 grid(NUM_GENES / TILE_GENES, BATCH / ROWS_PER_BLOCK);  // (20, 32)
    dlge_fused<<<grid, 256, 0, stream>>>(x, emb, W, b, y);
}

// Round 3
// 34.635 us; speedup vs baseline: 1.6819x; 1.6819x over previous
//
#include <hip/hip_runtime.h>

#define BATCH 1024
#define NUM_GENES 20000
#define NONGENE_DIM 64
#define EMB_DIM 32
#define INPUT_DIM (NUM_GENES + NONGENE_DIM)   // 20064
#define G4 (NUM_GENES / 4)                    // 5000 float4 per output row
#define ROWS_PER_BLOCK 4

// ws layout: [0 .. NUM_GENES)             gene_term[g]
//            [NUM_GENES .. NUM_GENES+B)   ng_term[i] + b
//
// Precompute: 8 lanes per gene (coalesced float4 emb reads, width-8 shuffle
// reduce) + 16 lanes per batch-row for ng_term. 176384 threads = 689 blocks.
#define GENE_THREADS (NUM_GENES * 8)              // 160000
#define NG_THREADS   (BATCH * 16)                 // 16384
#define PRE_TOTAL    (GENE_THREADS + NG_THREADS)  // 176384 = 689 * 256

__global__ __launch_bounds__(256)
void dlge_precompute(const float* __restrict__ x,
                     const float* __restrict__ emb,
                     const float* __restrict__ W,
                     const float* __restrict__ bptr,
                     float* __restrict__ ws) {
    const int tid = blockIdx.x * blockDim.x + threadIdx.x;

    if (tid < GENE_THREADS) {
        // gene_term[g] = dot(emb[g,:], W[65:97]); 8 lanes/gene, lane k owns
        // dims 4k..4k+3. Lane k of gene g reads emb[g*32 + 4k] -> consecutive
        // lanes read consecutive 16B -> fully coalesced.
        const int g = tid >> 3;
        const int k = tid & 7;
        const float4 e = reinterpret_cast<const float4*>(emb)[g * (EMB_DIM / 4) + k];
        float p = e.x * W[NONGENE_DIM + 1 + 4 * k + 0]
                + e.y * W[NONGENE_DIM + 1 + 4 * k + 1]
                + e.z * W[NONGENE_DIM + 1 + 4 * k + 2]
                + e.w * W[NONGENE_DIM + 1 + 4 * k + 3];
        p += __shfl_down(p, 4, 8);
        p += __shfl_down(p, 2, 8);
        p += __shfl_down(p, 1, 8);
        if (k == 0) ws[g] = p;
    } else if (tid < PRE_TOTAL) {
        // ng_term[row] + b; 16 lanes/row, lane k owns dims 4k..4k+3 (coalesced
        // 256B per row).
        const int t   = tid - GENE_THREADS;
        const int row = t >> 4;
        const int k   = t & 15;
        const float4 v = reinterpret_cast<const float4*>(
            x + (size_t)row * INPUT_DIM + NUM_GENES)[k];
        float p = v.x * W[4 * k + 0] + v.y * W[4 * k + 1]
                + v.z * W[4 * k + 2] + v.w * W[4 * k + 3];
        p += __shfl_down(p, 8, 16);
        p += __shfl_down(p, 4, 16);
        p += __shfl_down(p, 2, 16);
        p += __shfl_down(p, 1, 16);
        if (k == 0) ws[NUM_GENES + row] = p + bptr[0];
    }
}

// Main pass: block = (column-tile of 256 float4) x (4 rows). Each thread owns
// one float4 column j and 4 rows: g4 loaded once, 4 independent
// load->fma->store chains (ILP), fully coalesced.
__global__ __launch_bounds__(256)
void dlge_main(const float* __restrict__ x,
               const float* __restrict__ ws,
               const float* __restrict__ W,
               float* __restrict__ y) {
    const int j = blockIdx.x * 256 + threadIdx.x;    // float4 column 0..5119
    if (j >= G4) return;
    const int row0 = blockIdx.y * ROWS_PER_BLOCK;

    const float wx = W[NONGENE_DIM];
    const float4 g4 = reinterpret_cast<const float4*>(ws)[j];

    float s[ROWS_PER_BLOCK];
#pragma unroll
    for (int r = 0; r < ROWS_PER_BLOCK; ++r)
        s[r] = ws[NUM_GENES + row0 + r];             // uniform -> scalar loads

    float4 x4[ROWS_PER_BLOCK];
#pragma unroll
    for (int r = 0; r < ROWS_PER_BLOCK; ++r)
        x4[r] = reinterpret_cast<const float4*>(
            x + (size_t)(row0 + r) * INPUT_DIM)[j];

#pragma unroll
    for (int r = 0; r < ROWS_PER_BLOCK; ++r) {
        float4 o;
        o.x = s[r] + x4[r].x * wx + g4.x;
        o.y = s[r] + x4[r].y * wx + g4.y;
        o.z = s[r] + x4[r].z * wx + g4.z;
        o.w = s[r] + x4[r].w * wx + g4.w;
        reinterpret_cast<float4*>(y + (size_t)(row0 + r) * NUM_GENES)[j] = o;
    }
}

extern "C" void kernel_launch(void* const* d_in, const int* in_sizes, int n_in,
                              void* d_out, int out_size, void* d_ws, size_t ws_size,
                              hipStream_t stream) {
    const float* x   = (const float*)d_in[0];
    const float* emb = (const float*)d_in[1];
    const float* W   = (const float*)d_in[2];
    const float* b   = (const float*)d_in[3];
    float* y  = (float*)d_out;
    float* ws = (float*)d_ws;

    dlge_precompute<<<PRE_TOTAL / 256, 256, 0, stream>>>(x, emb, W, b, ws);

    dim3 grid((G4 + 255) / 256, BATCH / ROWS_PER_BLOCK);   // (20, 256)
    dlge_main<<<grid, 256, 0, stream>>>(x, ws, W, y);
}

// Round 4
// 33.671 us; speedup vs baseline: 1.7301x; 1.0286x over previous
//
#include <hip/hip_runtime.h>

#define BATCH 1024
#define NUM_GENES 20000
#define NONGENE_DIM 64
#define EMB_DIM 32
#define INPUT_DIM (NUM_GENES + NONGENE_DIM)   // 20064
#define G4 (NUM_GENES / 4)                    // 5000 float4 per output row
#define IN4 (INPUT_DIM / 4)                   // 5016 float4 per input row

// ws layout: [0 .. NUM_GENES)             gene_term[g]
//            [NUM_GENES .. NUM_GENES+B)   ng_term[i] + b
#define GENE_THREADS (NUM_GENES * 8)              // 160000
#define NG_THREADS   (BATCH * 16)                 // 16384
#define PRE_TOTAL    (GENE_THREADS + NG_THREADS)  // 176384 = 689 * 256

__global__ __launch_bounds__(256)
void dlge_precompute(const float* __restrict__ x,
                     const float* __restrict__ emb,
                     const float* __restrict__ W,
                     const float* __restrict__ bptr,
                     float* __restrict__ ws) {
    const int tid = blockIdx.x * blockDim.x + threadIdx.x;

    if (tid < GENE_THREADS) {
        // gene_term[g] = dot(emb[g,:], W[65:97]); 8 lanes/gene, coalesced.
        const int g = tid >> 3;
        const int k = tid & 7;
        const float4 e = reinterpret_cast<const float4*>(emb)[g * (EMB_DIM / 4) + k];
        float p = e.x * W[NONGENE_DIM + 1 + 4 * k + 0]
                + e.y * W[NONGENE_DIM + 1 + 4 * k + 1]
                + e.z * W[NONGENE_DIM + 1 + 4 * k + 2]
                + e.w * W[NONGENE_DIM + 1 + 4 * k + 3];
        p += __shfl_down(p, 4, 8);
        p += __shfl_down(p, 2, 8);
        p += __shfl_down(p, 1, 8);
        if (k == 0) ws[g] = p;
    } else if (tid < PRE_TOTAL) {
        // ng_term[row] + b; 16 lanes/row, coalesced 256B per row.
        const int t   = tid - GENE_THREADS;
        const int row = t >> 4;
        const int k   = t & 15;
        const float4 v = reinterpret_cast<const float4*>(
            x + (size_t)row * INPUT_DIM + NUM_GENES)[k];
        float p = v.x * W[4 * k + 0] + v.y * W[4 * k + 1]
                + v.z * W[4 * k + 2] + v.w * W[4 * k + 3];
        p += __shfl_down(p, 8, 16);
        p += __shfl_down(p, 4, 16);
        p += __shfl_down(p, 2, 16);
        p += __shfl_down(p, 1, 16);
        if (k == 0) ws[NUM_GENES + row] = p + bptr[0];
    }
}

// Main pass: LINEAR sweep over flattened y (1024*5000 float4s). Block b owns
// float4s [b*2048, (b+1)*2048) -> writes are one contiguous 32KB run per
// block, globally a linear sweep (same pattern as the 7 TB/s fill kernel).
// 8 float4 per thread = deep outstanding-load queue.
#define F4_TOTAL (BATCH * G4)                 // 5,120,000
#define F4_PER_BLOCK 2048
#define N_BLOCKS (F4_TOTAL / F4_PER_BLOCK)    // 2500

__global__ __launch_bounds__(256)
void dlge_main(const float* __restrict__ x,
               const float* __restrict__ ws,
               const float* __restrict__ W,
               float* __restrict__ y) {
    const float wx = W[NONGENE_DIM];
    const int base = blockIdx.x * F4_PER_BLOCK + threadIdx.x;

    const float4* __restrict__ xf4  = reinterpret_cast<const float4*>(x);
    const float4* __restrict__ gtf4 = reinterpret_cast<const float4*>(ws);
    float4* __restrict__ yf4        = reinterpret_cast<float4*>(y);

    int   row[8], col[8];
    float4 xv[8], gv[8];
    float  sv[8];

#pragma unroll
    for (int k = 0; k < 8; ++k) {
        const int j = base + k * 256;              // flat float4 index
        row[k] = (unsigned)j / (unsigned)G4;       // compiler magic-div
        col[k] = j - row[k] * G4;
    }
#pragma unroll
    for (int k = 0; k < 8; ++k)
        xv[k] = xf4[(size_t)row[k] * IN4 + col[k]];
#pragma unroll
    for (int k = 0; k < 8; ++k)
        gv[k] = gtf4[col[k]];
#pragma unroll
    for (int k = 0; k < 8; ++k)
        sv[k] = ws[NUM_GENES + row[k]];            // ng_term[row]+b (L1/L2 hit)

#pragma unroll
    for (int k = 0; k < 8; ++k) {
        float4 o;
        o.x = sv[k] + xv[k].x * wx + gv[k].x;
        o.y = sv[k] + xv[k].y * wx + gv[k].y;
        o.z = sv[k] + xv[k].z * wx + gv[k].z;
        o.w = sv[k] + xv[k].w * wx + gv[k].w;
        yf4[(size_t)row[k] * G4 + col[k]] = o;
    }
}

extern "C" void kernel_launch(void* const* d_in, const int* in_sizes, int n_in,
                              void* d_out, int out_size, void* d_ws, size_t ws_size,
                              hipStream_t stream) {
    const float* x   = (const float*)d_in[0];
    const float* emb = (const float*)d_in[1];
    const float* W   = (const float*)d_in[2];
    const float* b   = (const float*)d_in[3];
    float* y  = (float*)d_out;
    float* ws = (float*)d_ws;

    dlge_precompute<<<PRE_TOTAL / 256, 256, 0, stream>>>(x, emb, W, b, ws);
    dlge_main<<<N_BLOCKS, 256, 0, stream>>>(x, ws, W, y);
}